// Round 1
// baseline (294.252 us; speedup 1.0000x reference)
//
#include <hip/hip_runtime.h>

// Model: generalized multinomial clique objective over 2- and 3-simplices.
// out = 2*obj2 + 4*obj3 where
//   obj2 = sum_edges (1 - 0.5 * p.q)
//   obj3 = sum_tris  (2 - p.q - p.r - q.r + (4/3) * sum_a p_a q_a r_a)
// with P = row-softmax of the scattered node-parameter matrix (n_L == 4).

#define NL 4

__device__ __forceinline__ float dot4(float4 a, float4 b) {
    return a.x * b.x + a.y * b.y + a.z * b.z + a.w * b.w;
}

__global__ void softmax_rows(const float* __restrict__ trainable,
                             const float* __restrict__ fixedp,
                             const int* __restrict__ fixed_idx,
                             float* __restrict__ P,
                             int n_fixed, int n_total) {
    int i = blockIdx.x * blockDim.x + threadIdx.x;
    if (i >= n_total) return;
    float4 v;
    int dst;
    if (i < n_fixed) {
        v = ((const float4*)fixedp)[i];
        dst = fixed_idx[i];
    } else {
        v = ((const float4*)trainable)[i - n_fixed];
        dst = i;  // trainable_indices = arange(n_fixed, n_V)
    }
    float m = fmaxf(fmaxf(v.x, v.y), fmaxf(v.z, v.w));
    float ex = __expf(v.x - m), ey = __expf(v.y - m);
    float ez = __expf(v.z - m), ew = __expf(v.w - m);
    float inv = 1.0f / (ex + ey + ez + ew);
    ((float4*)P)[dst] = make_float4(ex * inv, ey * inv, ez * inv, ew * inv);
}

// Each thread handles 4 edges (2x int4 index loads = 32B coalesced).
__global__ void edge_reduce(const int* __restrict__ s2, int S2,
                            const float* __restrict__ P,
                            float* __restrict__ acc_dot) {
    int quad = blockIdx.x * blockDim.x + threadIdx.x;
    const float4* __restrict__ Pv = (const float4*)P;
    float sum = 0.f;
    int base = quad * 4;
    if (base + 4 <= S2) {
        int4 a = ((const int4*)s2)[quad * 2];
        int4 b = ((const int4*)s2)[quad * 2 + 1];
        sum += dot4(Pv[a.x], Pv[a.y]);
        sum += dot4(Pv[a.z], Pv[a.w]);
        sum += dot4(Pv[b.x], Pv[b.y]);
        sum += dot4(Pv[b.z], Pv[b.w]);
    } else {
        for (int e = base; e < S2; ++e) {
            sum += dot4(Pv[s2[2 * e]], Pv[s2[2 * e + 1]]);
        }
    }
    // wave(64) reduce, then one atomic per wave
    #pragma unroll
    for (int off = 32; off > 0; off >>= 1) sum += __shfl_down(sum, off, 64);
    if ((threadIdx.x & 63) == 0) atomicAdd(acc_dot, sum);
}

// Each thread handles 4 triples (3x int4 index loads = 48B coalesced).
// acc[0] += sum(u+v+w); acc[1] += sum(t)
__global__ void tri_reduce(const int* __restrict__ s3, int S3,
                           const float* __restrict__ P,
                           float* __restrict__ acc) {
    int quad = blockIdx.x * blockDim.x + threadIdx.x;
    const float4* __restrict__ Pv = (const float4*)P;
    float s_uvw = 0.f, s_t = 0.f;
    int base = quad * 4;
    int i0[4], i1[4], i2[4];
    int n = 0;
    if (base + 4 <= S3) {
        int4 a = ((const int4*)s3)[quad * 3];
        int4 b = ((const int4*)s3)[quad * 3 + 1];
        int4 c = ((const int4*)s3)[quad * 3 + 2];
        i0[0] = a.x; i1[0] = a.y; i2[0] = a.z;
        i0[1] = a.w; i1[1] = b.x; i2[1] = b.y;
        i0[2] = b.z; i1[2] = b.w; i2[2] = c.x;
        i0[3] = c.y; i1[3] = c.z; i2[3] = c.w;
        n = 4;
    } else {
        for (int e = base; e < S3; ++e) {
            i0[n] = s3[3 * e]; i1[n] = s3[3 * e + 1]; i2[n] = s3[3 * e + 2];
            ++n;
        }
    }
    for (int k = 0; k < n; ++k) {
        float4 p = Pv[i0[k]], q = Pv[i1[k]], r = Pv[i2[k]];
        s_uvw += dot4(p, q) + dot4(p, r) + dot4(q, r);
        s_t += p.x * q.x * r.x + p.y * q.y * r.y + p.z * q.z * r.z + p.w * q.w * r.w;
    }
    #pragma unroll
    for (int off = 32; off > 0; off >>= 1) {
        s_uvw += __shfl_down(s_uvw, off, 64);
        s_t   += __shfl_down(s_t,   off, 64);
    }
    if ((threadIdx.x & 63) == 0) {
        atomicAdd(&acc[0], s_uvw);
        atomicAdd(&acc[1], s_t);
    }
}

__global__ void finalize(const float* __restrict__ acc,
                         float* __restrict__ out, float S2f, float S3f) {
    float obj2 = S2f - 0.5f * acc[0];
    float obj3 = 2.f * S3f - acc[1] + (4.f / 3.f) * acc[2];
    out[0] = 2.f * obj2 + 4.f * obj3;
}

extern "C" void kernel_launch(void* const* d_in, const int* in_sizes, int n_in,
                              void* d_out, int out_size, void* d_ws, size_t ws_size,
                              hipStream_t stream) {
    const float* trainable = (const float*)d_in[0];
    const float* fixedp    = (const float*)d_in[1];
    const int*   fixed_idx = (const int*)d_in[2];
    const int*   s2        = (const int*)d_in[3];
    const int*   s3        = (const int*)d_in[4];

    int n_fixed = in_sizes[2];
    int n_L     = in_sizes[1] / n_fixed;   // == 4
    int n_train = in_sizes[0] / n_L;
    int n_V     = n_fixed + n_train;
    int S2      = in_sizes[3] / 2;
    int S3      = in_sizes[4] / 3;
    (void)n_L; (void)ws_size; (void)n_in; (void)out_size;

    float* P   = (float*)d_ws;                 // n_V * 4 floats
    float* acc = P + (size_t)n_V * NL;         // acc[0]=dot2, acc[1]=uvw, acc[2]=t

    hipMemsetAsync(acc, 0, 3 * sizeof(float), stream);

    softmax_rows<<<(n_V + 255) / 256, 256, 0, stream>>>(
        trainable, fixedp, fixed_idx, P, n_fixed, n_V);

    int nq2 = (S2 + 3) / 4;
    edge_reduce<<<(nq2 + 255) / 256, 256, 0, stream>>>(s2, S2, P, &acc[0]);

    int nq3 = (S3 + 3) / 4;
    tri_reduce<<<(nq3 + 255) / 256, 256, 0, stream>>>(s3, S3, P, &acc[1]);

    finalize<<<1, 1, 0, stream>>>(acc, (float*)d_out, (float)S2, (float)S3);
}

// Round 2
// 114.199 us; speedup vs baseline: 2.5767x; 2.5767x over previous
//
#include <hip/hip_runtime.h>

// Model: generalized multinomial clique objective over 2- and 3-simplices.
// out = 2*obj2 + 4*obj3 where
//   obj2 = sum_edges (1 - 0.5 * p.q)
//   obj3 = sum_tris  (2 - p.q - p.r - q.r + (4/3) * sum_a p_a q_a r_a)
// with P = row-softmax of the scattered node-parameter matrix (n_L == 4).
//
// R1: removed same-cache-line atomics (34 cyc/atomic serialization was 70% of
// runtime). Blocks write partials to distinct slots; final kernel reduces.

#define NL 4

__device__ __forceinline__ float dot4(float4 a, float4 b) {
    return a.x * b.x + a.y * b.y + a.z * b.z + a.w * b.w;
}

__global__ void softmax_rows(const float* __restrict__ trainable,
                             const float* __restrict__ fixedp,
                             const int* __restrict__ fixed_idx,
                             float* __restrict__ P,
                             int n_fixed, int n_total) {
    int i = blockIdx.x * blockDim.x + threadIdx.x;
    if (i >= n_total) return;
    float4 v;
    int dst;
    if (i < n_fixed) {
        v = ((const float4*)fixedp)[i];
        dst = fixed_idx[i];
    } else {
        v = ((const float4*)trainable)[i - n_fixed];
        dst = i;  // trainable_indices = arange(n_fixed, n_V)
    }
    float m = fmaxf(fmaxf(v.x, v.y), fmaxf(v.z, v.w));
    float ex = __expf(v.x - m), ey = __expf(v.y - m);
    float ez = __expf(v.z - m), ew = __expf(v.w - m);
    float inv = 1.0f / (ex + ey + ez + ew);
    ((float4*)P)[dst] = make_float4(ex * inv, ey * inv, ez * inv, ew * inv);
}

// 8 edges per thread (4x int4 index loads), block-reduce, one partial per block.
__global__ void edge_reduce(const int* __restrict__ s2, int S2,
                            const float* __restrict__ P,
                            float* __restrict__ part2) {
    const float4* __restrict__ Pv = (const float4*)P;
    int tid = blockIdx.x * blockDim.x + threadIdx.x;
    int base = tid * 8;
    float sum = 0.f;
    if (base + 8 <= S2) {
        const int4* s = (const int4*)s2;
        int4 a = s[base / 2], b = s[base / 2 + 1];
        int4 c = s[base / 2 + 2], d = s[base / 2 + 3];
        float4 p0 = Pv[a.x], q0 = Pv[a.y];
        float4 p1 = Pv[a.z], q1 = Pv[a.w];
        float4 p2 = Pv[b.x], q2 = Pv[b.y];
        float4 p3 = Pv[b.z], q3 = Pv[b.w];
        float4 p4 = Pv[c.x], q4 = Pv[c.y];
        float4 p5 = Pv[c.z], q5 = Pv[c.w];
        float4 p6 = Pv[d.x], q6 = Pv[d.y];
        float4 p7 = Pv[d.z], q7 = Pv[d.w];
        sum = dot4(p0, q0) + dot4(p1, q1) + dot4(p2, q2) + dot4(p3, q3)
            + dot4(p4, q4) + dot4(p5, q5) + dot4(p6, q6) + dot4(p7, q7);
    } else {
        for (int e = base; e < S2; ++e)
            sum += dot4(Pv[s2[2 * e]], Pv[s2[2 * e + 1]]);
    }
    #pragma unroll
    for (int off = 32; off > 0; off >>= 1) sum += __shfl_down(sum, off, 64);
    __shared__ float lds[4];
    int wid = threadIdx.x >> 6;
    if ((threadIdx.x & 63) == 0) lds[wid] = sum;
    __syncthreads();
    if (threadIdx.x == 0)
        part2[blockIdx.x] = lds[0] + lds[1] + lds[2] + lds[3];
}

// 8 triples per thread (6x int4 index loads), block-reduce, 2 partials/block.
__global__ void tri_reduce(const int* __restrict__ s3, int S3,
                           const float* __restrict__ P,
                           float* __restrict__ part3) {
    const float4* __restrict__ Pv = (const float4*)P;
    int tid = blockIdx.x * blockDim.x + threadIdx.x;
    int base = tid * 8;
    float s_uvw = 0.f, s_t = 0.f;
    if (base + 8 <= S3) {
        const int4* s = (const int4*)s3;
        int vbase = (3 * base) / 4;
        int4 a = s[vbase],     b = s[vbase + 1], c = s[vbase + 2];
        int4 d = s[vbase + 3], e = s[vbase + 4], f = s[vbase + 5];
        int i0[8] = {a.x, a.w, b.z, c.y, d.x, d.w, e.z, f.y};
        int i1[8] = {a.y, b.x, b.w, c.z, d.y, e.x, e.w, f.z};
        int i2[8] = {a.z, b.y, c.x, c.w, d.z, e.y, f.x, f.w};
        #pragma unroll
        for (int k = 0; k < 8; ++k) {
            float4 p = Pv[i0[k]], q = Pv[i1[k]], r = Pv[i2[k]];
            s_uvw += dot4(p, q) + dot4(p, r) + dot4(q, r);
            s_t += p.x * q.x * r.x + p.y * q.y * r.y
                 + p.z * q.z * r.z + p.w * q.w * r.w;
        }
    } else {
        for (int e2 = base; e2 < S3; ++e2) {
            float4 p = Pv[s3[3 * e2]], q = Pv[s3[3 * e2 + 1]], r = Pv[s3[3 * e2 + 2]];
            s_uvw += dot4(p, q) + dot4(p, r) + dot4(q, r);
            s_t += p.x * q.x * r.x + p.y * q.y * r.y
                 + p.z * q.z * r.z + p.w * q.w * r.w;
        }
    }
    #pragma unroll
    for (int off = 32; off > 0; off >>= 1) {
        s_uvw += __shfl_down(s_uvw, off, 64);
        s_t   += __shfl_down(s_t,   off, 64);
    }
    __shared__ float lds[8];
    int wid = threadIdx.x >> 6;
    if ((threadIdx.x & 63) == 0) { lds[wid] = s_uvw; lds[4 + wid] = s_t; }
    __syncthreads();
    if (threadIdx.x == 0) {
        part3[2 * blockIdx.x]     = lds[0] + lds[1] + lds[2] + lds[3];
        part3[2 * blockIdx.x + 1] = lds[4] + lds[5] + lds[6] + lds[7];
    }
}

__global__ void final_combine(const float* __restrict__ part2, int nb2,
                              const float* __restrict__ part3, int nb3,
                              float* __restrict__ out, float S2f, float S3f) {
    float dot2 = 0.f, uvw = 0.f, t = 0.f;
    for (int i = threadIdx.x; i < nb2; i += 256) dot2 += part2[i];
    for (int i = threadIdx.x; i < nb3; i += 256) {
        uvw += part3[2 * i];
        t   += part3[2 * i + 1];
    }
    #pragma unroll
    for (int off = 32; off > 0; off >>= 1) {
        dot2 += __shfl_down(dot2, off, 64);
        uvw  += __shfl_down(uvw,  off, 64);
        t    += __shfl_down(t,    off, 64);
    }
    __shared__ float lds[12];
    int wid = threadIdx.x >> 6;
    if ((threadIdx.x & 63) == 0) {
        lds[wid] = dot2; lds[4 + wid] = uvw; lds[8 + wid] = t;
    }
    __syncthreads();
    if (threadIdx.x == 0) {
        float D = lds[0] + lds[1] + lds[2] + lds[3];
        float U = lds[4] + lds[5] + lds[6] + lds[7];
        float T = lds[8] + lds[9] + lds[10] + lds[11];
        float obj2 = S2f - 0.5f * D;
        float obj3 = 2.f * S3f - U + (4.f / 3.f) * T;
        out[0] = 2.f * obj2 + 4.f * obj3;
    }
}

extern "C" void kernel_launch(void* const* d_in, const int* in_sizes, int n_in,
                              void* d_out, int out_size, void* d_ws, size_t ws_size,
                              hipStream_t stream) {
    const float* trainable = (const float*)d_in[0];
    const float* fixedp    = (const float*)d_in[1];
    const int*   fixed_idx = (const int*)d_in[2];
    const int*   s2        = (const int*)d_in[3];
    const int*   s3        = (const int*)d_in[4];

    int n_fixed = in_sizes[2];
    int n_L     = in_sizes[1] / n_fixed;   // == 4
    int n_train = in_sizes[0] / n_L;
    int n_V     = n_fixed + n_train;
    int S2      = in_sizes[3] / 2;
    int S3      = in_sizes[4] / 3;
    (void)n_L; (void)ws_size; (void)n_in; (void)out_size;

    float* P     = (float*)d_ws;                  // n_V * 4 floats
    float* part2 = P + (size_t)n_V * NL;
    int threads2 = (S2 + 7) / 8;
    int nb2      = (threads2 + 255) / 256;
    float* part3 = part2 + nb2;
    int threads3 = (S3 + 7) / 8;
    int nb3      = (threads3 + 255) / 256;

    softmax_rows<<<(n_V + 255) / 256, 256, 0, stream>>>(
        trainable, fixedp, fixed_idx, P, n_fixed, n_V);

    edge_reduce<<<nb2, 256, 0, stream>>>(s2, S2, P, part2);
    tri_reduce<<<nb3, 256, 0, stream>>>(s3, S3, P, part3);

    final_combine<<<1, 256, 0, stream>>>(part2, nb2, part3, nb3,
                                         (float*)d_out, (float)S2, (float)S3);
}

// Round 3
// 111.579 us; speedup vs baseline: 2.6372x; 1.0235x over previous
//
#include <hip/hip_runtime.h>

// Model: generalized multinomial clique objective over 2- and 3-simplices.
// out = 2*obj2 + 4*obj3 where
//   obj2 = sum_edges (1 - 0.5 * p.q)
//   obj3 = sum_tris  (2 - p.q - p.r - q.r + (4/3) * sum_a p_a q_a r_a)
// with P = row-softmax of the scattered node-parameter matrix (n_L == 4).
//
// R1: removed same-cache-line atomics (were 34 cyc/atomic serialized).
// R2: occupancy was grid-limited (8 items/thread -> 489 blocks -> 24%).
//     4 items/thread + fused edge+tri kernel -> ~3k blocks, full occupancy,
//     both gather streams overlap.

#define NL 4

__device__ __forceinline__ float dot4(float4 a, float4 b) {
    return a.x * b.x + a.y * b.y + a.z * b.z + a.w * b.w;
}

__global__ void softmax_rows(const float* __restrict__ trainable,
                             const float* __restrict__ fixedp,
                             const int* __restrict__ fixed_idx,
                             float* __restrict__ P,
                             int n_fixed, int n_total) {
    int i = blockIdx.x * blockDim.x + threadIdx.x;
    if (i >= n_total) return;
    float4 v;
    int dst;
    if (i < n_fixed) {
        v = ((const float4*)fixedp)[i];
        dst = fixed_idx[i];
    } else {
        v = ((const float4*)trainable)[i - n_fixed];
        dst = i;  // trainable_indices = arange(n_fixed, n_V)
    }
    float m = fmaxf(fmaxf(v.x, v.y), fmaxf(v.z, v.w));
    float ex = __expf(v.x - m), ey = __expf(v.y - m);
    float ez = __expf(v.z - m), ew = __expf(v.w - m);
    float inv = 1.0f / (ex + ey + ez + ew);
    ((float4*)P)[dst] = make_float4(ex * inv, ey * inv, ez * inv, ew * inv);
}

// Fused gather-reduce. Blocks [0, nb2): 4 edges/thread. Blocks [nb2, nb2+nb3):
// 4 triples/thread. Block-level partials to distinct slots (no atomics).
__global__ void gather_reduce(const int* __restrict__ s2, int S2, int nb2,
                              const int* __restrict__ s3, int S3,
                              const float* __restrict__ P,
                              float* __restrict__ part2,
                              float* __restrict__ part3) {
    const float4* __restrict__ Pv = (const float4*)P;
    __shared__ float lds[8];
    int wid = threadIdx.x >> 6;

    if ((int)blockIdx.x < nb2) {
        int tid = blockIdx.x * blockDim.x + threadIdx.x;
        int base = tid * 4;
        float sum = 0.f;
        if (base + 4 <= S2) {
            const int4* s = (const int4*)s2;
            int4 a = s[tid * 2], b = s[tid * 2 + 1];
            float4 p0 = Pv[a.x], q0 = Pv[a.y];
            float4 p1 = Pv[a.z], q1 = Pv[a.w];
            float4 p2 = Pv[b.x], q2 = Pv[b.y];
            float4 p3 = Pv[b.z], q3 = Pv[b.w];
            sum = dot4(p0, q0) + dot4(p1, q1) + dot4(p2, q2) + dot4(p3, q3);
        } else {
            for (int e = base; e < S2; ++e)
                sum += dot4(Pv[s2[2 * e]], Pv[s2[2 * e + 1]]);
        }
        #pragma unroll
        for (int off = 32; off > 0; off >>= 1) sum += __shfl_down(sum, off, 64);
        if ((threadIdx.x & 63) == 0) lds[wid] = sum;
        __syncthreads();
        if (threadIdx.x == 0)
            part2[blockIdx.x] = lds[0] + lds[1] + lds[2] + lds[3];
    } else {
        int bb = blockIdx.x - nb2;
        int tid = bb * blockDim.x + threadIdx.x;
        int base = tid * 4;
        float s_uvw = 0.f, s_t = 0.f;
        if (base + 4 <= S3) {
            const int4* s = (const int4*)s3;
            int4 a = s[tid * 3], b = s[tid * 3 + 1], c = s[tid * 3 + 2];
            int i0[4] = {a.x, a.w, b.z, c.y};
            int i1[4] = {a.y, b.x, b.w, c.z};
            int i2[4] = {a.z, b.y, c.x, c.w};
            float4 pp[4], qq[4], rr[4];
            #pragma unroll
            for (int k = 0; k < 4; ++k) {
                pp[k] = Pv[i0[k]]; qq[k] = Pv[i1[k]]; rr[k] = Pv[i2[k]];
            }
            #pragma unroll
            for (int k = 0; k < 4; ++k) {
                float4 p = pp[k], q = qq[k], r = rr[k];
                s_uvw += dot4(p, q) + dot4(p, r) + dot4(q, r);
                s_t += p.x * q.x * r.x + p.y * q.y * r.y
                     + p.z * q.z * r.z + p.w * q.w * r.w;
            }
        } else {
            for (int e = base; e < S3; ++e) {
                float4 p = Pv[s3[3 * e]], q = Pv[s3[3 * e + 1]], r = Pv[s3[3 * e + 2]];
                s_uvw += dot4(p, q) + dot4(p, r) + dot4(q, r);
                s_t += p.x * q.x * r.x + p.y * q.y * r.y
                     + p.z * q.z * r.z + p.w * q.w * r.w;
            }
        }
        #pragma unroll
        for (int off = 32; off > 0; off >>= 1) {
            s_uvw += __shfl_down(s_uvw, off, 64);
            s_t   += __shfl_down(s_t,   off, 64);
        }
        if ((threadIdx.x & 63) == 0) { lds[wid] = s_uvw; lds[4 + wid] = s_t; }
        __syncthreads();
        if (threadIdx.x == 0) {
            part3[2 * bb]     = lds[0] + lds[1] + lds[2] + lds[3];
            part3[2 * bb + 1] = lds[4] + lds[5] + lds[6] + lds[7];
        }
    }
}

__global__ void final_combine(const float* __restrict__ part2, int nb2,
                              const float* __restrict__ part3, int nb3,
                              float* __restrict__ out, float S2f, float S3f) {
    float dot2 = 0.f, uvw = 0.f, t = 0.f;
    for (int i = threadIdx.x; i < nb2; i += 256) dot2 += part2[i];
    for (int i = threadIdx.x; i < nb3; i += 256) {
        uvw += part3[2 * i];
        t   += part3[2 * i + 1];
    }
    #pragma unroll
    for (int off = 32; off > 0; off >>= 1) {
        dot2 += __shfl_down(dot2, off, 64);
        uvw  += __shfl_down(uvw,  off, 64);
        t    += __shfl_down(t,    off, 64);
    }
    __shared__ float lds[12];
    int wid = threadIdx.x >> 6;
    if ((threadIdx.x & 63) == 0) {
        lds[wid] = dot2; lds[4 + wid] = uvw; lds[8 + wid] = t;
    }
    __syncthreads();
    if (threadIdx.x == 0) {
        float D = lds[0] + lds[1] + lds[2] + lds[3];
        float U = lds[4] + lds[5] + lds[6] + lds[7];
        float T = lds[8] + lds[9] + lds[10] + lds[11];
        float obj2 = S2f - 0.5f * D;
        float obj3 = 2.f * S3f - U + (4.f / 3.f) * T;
        out[0] = 2.f * obj2 + 4.f * obj3;
    }
}

extern "C" void kernel_launch(void* const* d_in, const int* in_sizes, int n_in,
                              void* d_out, int out_size, void* d_ws, size_t ws_size,
                              hipStream_t stream) {
    const float* trainable = (const float*)d_in[0];
    const float* fixedp    = (const float*)d_in[1];
    const int*   fixed_idx = (const int*)d_in[2];
    const int*   s2        = (const int*)d_in[3];
    const int*   s3        = (const int*)d_in[4];

    int n_fixed = in_sizes[2];
    int n_L     = in_sizes[1] / n_fixed;   // == 4
    int n_train = in_sizes[0] / n_L;
    int n_V     = n_fixed + n_train;
    int S2      = in_sizes[3] / 2;
    int S3      = in_sizes[4] / 3;
    (void)n_L; (void)ws_size; (void)n_in; (void)out_size;

    float* P     = (float*)d_ws;                  // n_V * 4 floats
    float* part2 = P + (size_t)n_V * NL;
    int threads2 = (S2 + 3) / 4;
    int nb2      = (threads2 + 255) / 256;
    float* part3 = part2 + nb2;
    int threads3 = (S3 + 3) / 4;
    int nb3      = (threads3 + 255) / 256;

    softmax_rows<<<(n_V + 255) / 256, 256, 0, stream>>>(
        trainable, fixedp, fixed_idx, P, n_fixed, n_V);

    gather_reduce<<<nb2 + nb3, 256, 0, stream>>>(s2, S2, nb2, s3, S3, P,
                                                 part2, part3);

    final_combine<<<1, 256, 0, stream>>>(part2, nb2, part3, nb3,
                                         (float*)d_out, (float)S2, (float)S3);
}